// Round 2
// baseline (1902.538 us; speedup 1.0000x reference)
//
#include <hip/hip_runtime.h>
#include <hip/hip_bf16.h>

#define DIN 128
#define HID 32
#define EPS 1e-5f

// ---------- gcn_norm ----------
__global__ void deg_init(float* deg, int n) {
    int i = blockIdx.x * blockDim.x + threadIdx.x;
    if (i < n) deg[i] = 1.0f;  // self-loop weight
}

__global__ void deg_edges(const int* __restrict__ col, const float* __restrict__ w,
                          float* deg, int E) {
    int e = blockIdx.x * blockDim.x + threadIdx.x;
    if (e < E) atomicAdd(&deg[col[e]], w[e]);
}

// deg -> dinv in place; normself = dinv^2 (self-loop norm)
__global__ void dinv_kernel(float* deg, float* normself, int n) {
    int i = blockIdx.x * blockDim.x + threadIdx.x;
    if (i < n) {
        float dv = rsqrtf(deg[i]);  // deg >= 1 always (self loop)
        deg[i] = dv;
        normself[i] = dv * dv;
    }
}

__global__ void norm_edges(const int* __restrict__ row, const int* __restrict__ col,
                           const float* __restrict__ w, const float* __restrict__ dinv,
                           float* __restrict__ norm, int E) {
    int e = blockIdx.x * blockDim.x + threadIdx.x;
    if (e < E) norm[e] = dinv[row[e]] * w[e] * dinv[col[e]];
}

// ---------- GEMMs ----------
// h = x @ W0, x: [n,128] f32, W: [128,32] f32, h: [n,32] f32
__global__ void gemm_din(const float* __restrict__ x, const float* __restrict__ W,
                         float* __restrict__ h, int n) {
    __shared__ float Wl[DIN * HID];
    for (int i = threadIdx.x; i < DIN * HID; i += blockDim.x) Wl[i] = W[i];
    __syncthreads();
    int ch = threadIdx.x & 31;
    int node = blockIdx.x * 8 + (threadIdx.x >> 5);
    if (node >= n) return;
    const float* xr = x + (size_t)node * DIN;
    float acc = 0.f;
#pragma unroll 8
    for (int k = 0; k < DIN; ++k) acc += xr[k] * Wl[k * HID + ch];
    h[node * HID + ch] = acc;
}

// h = a @ W, a: [n,32] f32, W: [32,32] f32
__global__ void gemm_hid(const float* __restrict__ a, const float* __restrict__ W,
                         float* __restrict__ h, int n) {
    __shared__ float Wl[HID * HID];
    for (int i = threadIdx.x; i < HID * HID; i += blockDim.x) Wl[i] = W[i];
    __syncthreads();
    int ch = threadIdx.x & 31;
    int node = blockIdx.x * 8 + (threadIdx.x >> 5);
    if (node >= n) return;
    const float* ar = a + (size_t)node * HID;
    float acc = 0.f;
#pragma unroll
    for (int k = 0; k < HID; ++k) acc += ar[k] * Wl[k * HID + ch];
    h[node * HID + ch] = acc;
}

// ---------- aggregation ----------
// agg[i,ch] = normself[i]*h[i,ch] + b[ch]   (self loop + bias; no atomics needed)
__global__ void agg_init(const float* __restrict__ h, const float* __restrict__ normself,
                         const float* __restrict__ b, float* __restrict__ agg, int n) {
    int gid = blockIdx.x * blockDim.x + threadIdx.x;
    if (gid >= n * HID) return;
    int node = gid >> 5, ch = gid & 31;
    agg[gid] = normself[node] * h[gid] + b[ch];
}

// agg[col,ch] += norm[e] * h[row,ch]  (32 lanes per edge; coalesced gather + same-line atomics)
__global__ void agg_edges(const float* __restrict__ h, const int* __restrict__ row,
                          const int* __restrict__ col, const float* __restrict__ norm,
                          float* __restrict__ agg, int E) {
    int gid = blockIdx.x * blockDim.x + threadIdx.x;
    if (gid >= E * HID) return;
    int e = gid >> 5, ch = gid & 31;
    int r = row[e], c = col[e];
    atomicAdd(&agg[c * HID + ch], norm[e] * h[r * HID + ch]);
}

// ---------- batchnorm ----------
__global__ void zero_stats(float* s) {
    if (threadIdx.x < 64) s[threadIdx.x] = 0.f;
}

__global__ void bn_reduce(const float* __restrict__ agg, float* __restrict__ stats, int n) {
    __shared__ float s1[256], s2[256];
    int ch = threadIdx.x & 31, rg = threadIdx.x >> 5;
    float a = 0.f, b = 0.f;
    for (int node = blockIdx.x * 8 + rg; node < n; node += gridDim.x * 8) {
        float v = agg[node * HID + ch];
        a += v;
        b += v * v;
    }
    s1[threadIdx.x] = a;
    s2[threadIdx.x] = b;
    __syncthreads();
    if (threadIdx.x < 32) {
        float ta = 0.f, tb = 0.f;
#pragma unroll
        for (int j = 0; j < 8; ++j) {
            ta += s1[j * 32 + threadIdx.x];
            tb += s2[j * 32 + threadIdx.x];
        }
        atomicAdd(&stats[threadIdx.x], ta);
        atomicAdd(&stats[32 + threadIdx.x], tb);
    }
}

__global__ void bn_apply(const float* __restrict__ agg, const float* __restrict__ stats,
                         const float* __restrict__ g, const float* __restrict__ be,
                         float* __restrict__ out, int n, float invN) {
    int gid = blockIdx.x * blockDim.x + threadIdx.x;
    if (gid >= n * HID) return;
    int ch = gid & 31;
    float mu = stats[ch] * invN;
    float var = stats[32 + ch] * invN - mu * mu;
    float v = (agg[gid] - mu) * rsqrtf(var + EPS) * g[ch] + be[ch];
    out[gid] = fmaxf(v, 0.f);
}

__global__ void relu_store(const float* __restrict__ agg, float* __restrict__ out, int n) {
    int gid = blockIdx.x * blockDim.x + threadIdx.x;
    if (gid < n * HID) out[gid] = fmaxf(agg[gid], 0.f);
}

extern "C" void kernel_launch(void* const* d_in, const int* in_sizes, int n_in,
                              void* d_out, int out_size, void* d_ws, size_t ws_size,
                              hipStream_t stream) {
    const int N = in_sizes[0] / DIN;
    const int E = in_sizes[2];

    const float* x = (const float*)d_in[0];
    const int* ei = (const int*)d_in[1];
    const float* ew = (const float*)d_in[2];
    const int* row = ei;
    const int* col = ei + E;

    const float* Ws[4] = {(const float*)d_in[3], (const float*)d_in[5],
                          (const float*)d_in[7], (const float*)d_in[9]};
    const float* bs[4] = {(const float*)d_in[4], (const float*)d_in[6],
                          (const float*)d_in[8], (const float*)d_in[10]};
    const float* gs[3] = {(const float*)d_in[11], (const float*)d_in[13], (const float*)d_in[15]};
    const float* bes[3] = {(const float*)d_in[12], (const float*)d_in[14], (const float*)d_in[16]};

    // workspace layout (floats); total ~13.0M floats = 52.2 MB
    float* ws = (float*)d_ws;
    float* dinv = ws;                         // N (deg -> dinv in place)
    float* normself = dinv + N;               // N
    float* norm = normself + N;               // E
    float* hbuf = norm + E;                   // N*HID
    float* aggbuf = hbuf + (size_t)N * HID;   // N*HID
    float* actbuf = aggbuf + (size_t)N * HID; // N*HID
    float* stats = actbuf + (size_t)N * HID;  // 64

    const int B = 256;
    const int ngrid = (N + B - 1) / B;
    const int egrid = (E + B - 1) / B;
    const int ngrid32 = (N * HID + B - 1) / B;
    const int egrid32 = (int)(((long long)E * HID + B - 1) / B);
    const int nodeGrid = (N + 7) / 8;
    const float invN = 1.0f / (float)N;

    // gcn_norm
    deg_init<<<ngrid, B, 0, stream>>>(dinv, N);
    deg_edges<<<egrid, B, 0, stream>>>(col, ew, dinv, E);
    dinv_kernel<<<ngrid, B, 0, stream>>>(dinv, normself, N);
    norm_edges<<<egrid, B, 0, stream>>>(row, col, ew, dinv, norm, E);

    for (int l = 0; l < 4; ++l) {
        if (l == 0)
            gemm_din<<<nodeGrid, B, 0, stream>>>(x, Ws[0], hbuf, N);
        else
            gemm_hid<<<nodeGrid, B, 0, stream>>>(actbuf, Ws[l], hbuf, N);

        agg_init<<<ngrid32, B, 0, stream>>>(hbuf, normself, bs[l], aggbuf, N);
        agg_edges<<<egrid32, B, 0, stream>>>(hbuf, row, col, norm, aggbuf, E);

        if (l < 3) {
            zero_stats<<<1, 64, 0, stream>>>(stats);
            bn_reduce<<<512, B, 0, stream>>>(aggbuf, stats, N);
            bn_apply<<<ngrid32, B, 0, stream>>>(aggbuf, stats, gs[l], bes[l], actbuf, N, invN);
        } else {
            relu_store<<<ngrid32, B, 0, stream>>>(aggbuf, (float*)d_out, N);
        }
    }
}

// Round 3
// 1442.159 us; speedup vs baseline: 1.3192x; 1.3192x over previous
//
#include <hip/hip_runtime.h>
#include <hip/hip_bf16.h>

#define DIN 128
#define HID 32
#define EPS 1e-5f

// ---------------- setup: zero rowptr, deg=1 (self loop) ----------------
__global__ void init_misc(int* __restrict__ rowptr, float* __restrict__ deg, int n) {
    int i = blockIdx.x * blockDim.x + threadIdx.x;
    if (i <= n) rowptr[i] = 0;
    if (i < n) deg[i] = 1.0f;
}

// histogram of col + weighted in-degree, one pass over edges
__global__ void hist_deg(const int* __restrict__ col, const float* __restrict__ w,
                         int* __restrict__ rowptr, float* __restrict__ deg, int E) {
    int e = blockIdx.x * blockDim.x + threadIdx.x;
    if (e < E) {
        int c = col[e];
        atomicAdd(&rowptr[c], 1);
        atomicAdd(&deg[c], w[e]);
    }
}

__global__ void dinv_kernel(float* deg, int n) {
    int i = blockIdx.x * blockDim.x + threadIdx.x;
    if (i < n) deg[i] = rsqrtf(deg[i]);  // deg >= 1 (self loop), safe
}

// ---------------- exclusive scan over rowptr[0..n) ----------------
__global__ void scan_blocks(int* __restrict__ data, int* __restrict__ bsum, int n) {
    __shared__ int s[256];
    int i = blockIdx.x * 256 + threadIdx.x;
    int v = (i < n) ? data[i] : 0;
    s[threadIdx.x] = v;
    __syncthreads();
    for (int off = 1; off < 256; off <<= 1) {
        int t = (threadIdx.x >= off) ? s[threadIdx.x - off] : 0;
        __syncthreads();
        s[threadIdx.x] += t;
        __syncthreads();
    }
    if (i < n) data[i] = s[threadIdx.x] - v;  // exclusive
    if (threadIdx.x == 255) bsum[blockIdx.x] = s[255];
}

__global__ void scan_tops(int* __restrict__ bsum, int nb) {
    __shared__ int s[512];
    int v = (threadIdx.x < nb) ? bsum[threadIdx.x] : 0;
    s[threadIdx.x] = v;
    __syncthreads();
    for (int off = 1; off < 512; off <<= 1) {
        int t = (threadIdx.x >= off) ? s[threadIdx.x - off] : 0;
        __syncthreads();
        s[threadIdx.x] += t;
        __syncthreads();
    }
    if (threadIdx.x < nb) bsum[threadIdx.x] = s[threadIdx.x] - v;  // exclusive
}

__global__ void scan_addback(int* __restrict__ data, const int* __restrict__ bsum, int n) {
    int i = blockIdx.x * 256 + threadIdx.x;
    if (i < n) data[i] += bsum[blockIdx.x];
}

// ---------------- scatter into CSR (rowptr mutates start->end) ----------------
// esort[pos] = (src, norm) packed; after this kernel rowptr[c] == end offset of node c
__global__ void scatter_csr(const int* __restrict__ row, const int* __restrict__ col,
                            const float* __restrict__ w, const float* __restrict__ dinv,
                            int* __restrict__ rowptr, int2* __restrict__ esort, int E) {
    int e = blockIdx.x * blockDim.x + threadIdx.x;
    if (e < E) {
        int r = row[e], c = col[e];
        float nv = dinv[r] * w[e] * dinv[c];
        int pos = atomicAdd(&rowptr[c], 1);
        esort[pos] = make_int2(r, __float_as_int(nv));
    }
}

// ---------------- GEMMs ----------------
__global__ void gemm_din(const float* __restrict__ x, const float* __restrict__ W,
                         float* __restrict__ h, int n) {
    __shared__ float Wl[DIN * HID];
    for (int i = threadIdx.x; i < DIN * HID; i += blockDim.x) Wl[i] = W[i];
    __syncthreads();
    int ch = threadIdx.x & 31;
    int node = blockIdx.x * 8 + (threadIdx.x >> 5);
    if (node >= n) return;
    const float* xr = x + (size_t)node * DIN;
    float acc = 0.f;
#pragma unroll 8
    for (int k = 0; k < DIN; ++k) acc += xr[k] * Wl[k * HID + ch];
    h[node * HID + ch] = acc;
}

__global__ void gemm_hid(const float* __restrict__ a, const float* __restrict__ W,
                         float* __restrict__ h, int n) {
    __shared__ float Wl[HID * HID];
    for (int i = threadIdx.x; i < HID * HID; i += blockDim.x) Wl[i] = W[i];
    __syncthreads();
    int ch = threadIdx.x & 31;
    int node = blockIdx.x * 8 + (threadIdx.x >> 5);
    if (node >= n) return;
    const float* ar = a + (size_t)node * HID;
    float acc = 0.f;
#pragma unroll
    for (int k = 0; k < HID; ++k) acc += ar[k] * Wl[k * HID + ch];
    h[node * HID + ch] = acc;
}

// ---------------- CSR gather aggregation ----------------
// agg[i,ch] = dinv[i]^2 * h[i,ch] + b[ch] + sum_e norm[e]*h[src[e],ch]
// 32 lanes per node; optional fused ReLU (final layer writes d_out)
__global__ void gather_csr(const float* __restrict__ h, const int* __restrict__ rowptr,
                           const int2* __restrict__ esort, const float* __restrict__ dinv,
                           const float* __restrict__ b, float* __restrict__ agg,
                           int n, int do_relu) {
    int ch = threadIdx.x & 31;
    int node = blockIdx.x * 8 + (threadIdx.x >> 5);
    if (node >= n) return;
    int start = (node == 0) ? 0 : rowptr[node - 1];
    int end = rowptr[node];
    float dv = dinv[node];
    float acc = dv * dv * h[node * HID + ch] + b[ch];
    for (int j = start; j < end; ++j) {
        int2 ed = esort[j];
        acc += __int_as_float(ed.y) * h[ed.x * HID + ch];
    }
    if (do_relu) acc = fmaxf(acc, 0.f);
    agg[node * HID + ch] = acc;
}

// ---------------- batchnorm ----------------
__global__ void zero_stats(float* s) {
    if (threadIdx.x < 64) s[threadIdx.x] = 0.f;
}

__global__ void bn_reduce(const float* __restrict__ agg, float* __restrict__ stats, int n) {
    __shared__ float s1[256], s2[256];
    int ch = threadIdx.x & 31, rg = threadIdx.x >> 5;
    float a = 0.f, b = 0.f;
    for (int node = blockIdx.x * 8 + rg; node < n; node += gridDim.x * 8) {
        float v = agg[node * HID + ch];
        a += v;
        b += v * v;
    }
    s1[threadIdx.x] = a;
    s2[threadIdx.x] = b;
    __syncthreads();
    if (threadIdx.x < 32) {
        float ta = 0.f, tb = 0.f;
#pragma unroll
        for (int j = 0; j < 8; ++j) {
            ta += s1[j * 32 + threadIdx.x];
            tb += s2[j * 32 + threadIdx.x];
        }
        atomicAdd(&stats[threadIdx.x], ta);
        atomicAdd(&stats[32 + threadIdx.x], tb);
    }
}

// in-place BN + ReLU
__global__ void bn_apply(float* __restrict__ agg, const float* __restrict__ stats,
                         const float* __restrict__ g, const float* __restrict__ be,
                         int n, float invN) {
    int gid = blockIdx.x * blockDim.x + threadIdx.x;
    if (gid >= n * HID) return;
    int ch = gid & 31;
    float mu = stats[ch] * invN;
    float var = stats[32 + ch] * invN - mu * mu;
    float v = (agg[gid] - mu) * rsqrtf(var + EPS) * g[ch] + be[ch];
    agg[gid] = fmaxf(v, 0.f);
}

extern "C" void kernel_launch(void* const* d_in, const int* in_sizes, int n_in,
                              void* d_out, int out_size, void* d_ws, size_t ws_size,
                              hipStream_t stream) {
    const int N = in_sizes[0] / DIN;
    const int E = in_sizes[2];

    const float* x = (const float*)d_in[0];
    const int* ei = (const int*)d_in[1];
    const float* ew = (const float*)d_in[2];
    const int* row = ei;
    const int* col = ei + E;

    const float* Ws[4] = {(const float*)d_in[3], (const float*)d_in[5],
                          (const float*)d_in[7], (const float*)d_in[9]};
    const float* bs[4] = {(const float*)d_in[4], (const float*)d_in[6],
                          (const float*)d_in[8], (const float*)d_in[10]};
    const float* gs[3] = {(const float*)d_in[11], (const float*)d_in[13], (const float*)d_in[15]};
    const float* bes[3] = {(const float*)d_in[12], (const float*)d_in[14], (const float*)d_in[16]};

    // workspace layout (~52 MB, same footprint as round-2's passing layout)
    float* ws = (float*)d_ws;
    float* dinv = ws;                          // N floats (deg -> dinv in place)
    int* rowptr = (int*)(dinv + N);            // N+1 ints
    int2* esort = (int2*)(rowptr + N + 1);     // E int2 (src, norm)
    float* bufX = (float*)(esort + E);         // N*HID (act / agg)
    float* bufY = bufX + (size_t)N * HID;      // N*HID (gemm out)
    float* stats = bufY + (size_t)N * HID;     // 64
    int* bsum = (int*)(stats + 64);            // 512

    const int B = 256;
    const int ngrid = (N + B) / B;             // covers n+1 for init
    const int egrid = (E + B - 1) / B;
    const int ngrid32 = (N * HID + B - 1) / B;
    const int nodeGrid = (N + 7) / 8;
    const int scanBlocks = (N + 255) / 256;    // 391 <= 512
    const float invN = 1.0f / (float)N;

    // ---- build norm + CSR ----
    init_misc<<<ngrid, B, 0, stream>>>(rowptr, dinv, N);
    hist_deg<<<egrid, B, 0, stream>>>(col, ew, rowptr, dinv, E);
    dinv_kernel<<<ngrid, B, 0, stream>>>(dinv, N);
    scan_blocks<<<scanBlocks, 256, 0, stream>>>(rowptr, bsum, N);
    scan_tops<<<1, 512, 0, stream>>>(bsum, scanBlocks);
    scan_addback<<<scanBlocks, 256, 0, stream>>>(rowptr, bsum, N);
    scatter_csr<<<egrid, B, 0, stream>>>(row, col, ew, dinv, rowptr, esort, E);

    // ---- layers ----
    for (int l = 0; l < 4; ++l) {
        if (l == 0)
            gemm_din<<<nodeGrid, B, 0, stream>>>(x, Ws[0], bufY, N);
        else
            gemm_hid<<<nodeGrid, B, 0, stream>>>(bufX, Ws[l], bufY, N);

        if (l < 3) {
            gather_csr<<<nodeGrid, B, 0, stream>>>(bufY, rowptr, esort, dinv, bs[l],
                                                   bufX, N, 0);
            zero_stats<<<1, 64, 0, stream>>>(stats);
            bn_reduce<<<512, B, 0, stream>>>(bufX, stats, N);
            bn_apply<<<ngrid32, B, 0, stream>>>(bufX, stats, gs[l], bes[l], N, invN);
        } else {
            gather_csr<<<nodeGrid, B, 0, stream>>>(bufY, rowptr, esort, dinv, bs[l],
                                                   (float*)d_out, N, 1);
        }
    }
}

// Round 4
// 1278.229 us; speedup vs baseline: 1.4884x; 1.1282x over previous
//
#include <hip/hip_runtime.h>
#include <hip/hip_bf16.h>

#define DIN 128
#define HID 32
#define EPS 1e-5f
#define FXS 16777216.0f   // 2^24 fixed-point scale for deg accumulation
#define FXI 5.9604644775390625e-8f  // 2^-24

// ---------------- zero the u64 count/deg accumulator ----------------
__global__ void init_cnt(unsigned long long* __restrict__ cnt64, int n) {
    int i = blockIdx.x * blockDim.x + threadIdx.x;
    if (i < n) cnt64[i] = 0ull;
}

// ---------------- one u64 atomic per edge: count(hi32) + fixpoint deg(lo32) ----------------
// returned old hi32 = this edge's rank within its destination bin
__global__ void hist_rank(const int* __restrict__ col, const float* __restrict__ w,
                          unsigned long long* __restrict__ cnt64, int* __restrict__ rank,
                          int E) {
    int e = blockIdx.x * blockDim.x + threadIdx.x;
    if (e < E) {
        int c = col[e];
        unsigned int fx = (unsigned int)(w[e] * FXS + 0.5f);
        unsigned long long old =
            atomicAdd(&cnt64[c], (1ull << 32) | (unsigned long long)fx);
        rank[e] = (int)(old >> 32);
    }
}

// counts -> rowptr[i] (pre-scan), deg -> dinv
__global__ void finalize_deg(const unsigned long long* __restrict__ cnt64,
                             int* __restrict__ rowptr, float* __restrict__ dinv, int n) {
    int i = blockIdx.x * blockDim.x + threadIdx.x;
    if (i < n) {
        unsigned long long v = cnt64[i];
        rowptr[i] = (int)(v >> 32);
        float deg = 1.0f + (float)(unsigned int)v * FXI;  // +1 self loop
        dinv[i] = rsqrtf(deg);
    }
}

// ---------------- exclusive scan over rowptr[0..n) ----------------
__global__ void scan_blocks(int* __restrict__ data, int* __restrict__ bsum, int n) {
    __shared__ int s[256];
    int i = blockIdx.x * 256 + threadIdx.x;
    int v = (i < n) ? data[i] : 0;
    s[threadIdx.x] = v;
    __syncthreads();
    for (int off = 1; off < 256; off <<= 1) {
        int t = (threadIdx.x >= off) ? s[threadIdx.x - off] : 0;
        __syncthreads();
        s[threadIdx.x] += t;
        __syncthreads();
    }
    if (i < n) data[i] = s[threadIdx.x] - v;  // exclusive
    if (threadIdx.x == 255) bsum[blockIdx.x] = s[255];
}

__global__ void scan_tops(int* __restrict__ bsum, int nb) {
    __shared__ int s[512];
    int v = (threadIdx.x < nb) ? bsum[threadIdx.x] : 0;
    s[threadIdx.x] = v;
    __syncthreads();
    for (int off = 1; off < 512; off <<= 1) {
        int t = (threadIdx.x >= off) ? s[threadIdx.x - off] : 0;
        __syncthreads();
        s[threadIdx.x] += t;
        __syncthreads();
    }
    if (threadIdx.x < nb) bsum[threadIdx.x] = s[threadIdx.x] - v;  // exclusive
}

__global__ void scan_addback(int* __restrict__ data, const int* __restrict__ bsum,
                             int n, int E) {
    int i = blockIdx.x * 256 + threadIdx.x;
    if (i < n) data[i] += bsum[blockIdx.x];
    if (i == n) data[n] = E;  // sentinel end
}

// ---------------- atomic-free scatter into CSR ----------------
__global__ void scatter_pos(const int* __restrict__ row, const int* __restrict__ col,
                            const float* __restrict__ w, const float* __restrict__ dinv,
                            const int* __restrict__ rowptr, const int* __restrict__ rank,
                            int2* __restrict__ esort, int E) {
    int e = blockIdx.x * blockDim.x + threadIdx.x;
    if (e < E) {
        int r = row[e], c = col[e];
        float nv = dinv[r] * w[e] * dinv[c];
        int pos = rowptr[c] + rank[e];
        esort[pos] = make_int2(r, __float_as_int(nv));
    }
}

// ---------------- GEMMs ----------------
__global__ void gemm_din(const float* __restrict__ x, const float* __restrict__ W,
                         float* __restrict__ h, int n) {
    __shared__ float Wl[DIN * HID];
    for (int i = threadIdx.x; i < DIN * HID; i += blockDim.x) Wl[i] = W[i];
    __syncthreads();
    int ch = threadIdx.x & 31;
    int node = blockIdx.x * 8 + (threadIdx.x >> 5);
    if (node >= n) return;
    const float* xr = x + (size_t)node * DIN;
    float acc = 0.f;
#pragma unroll 8
    for (int k = 0; k < DIN; ++k) acc += xr[k] * Wl[k * HID + ch];
    h[node * HID + ch] = acc;
}

__global__ void gemm_hid(const float* __restrict__ a, const float* __restrict__ W,
                         float* __restrict__ h, int n) {
    __shared__ float Wl[HID * HID];
    for (int i = threadIdx.x; i < HID * HID; i += blockDim.x) Wl[i] = W[i];
    __syncthreads();
    int ch = threadIdx.x & 31;
    int node = blockIdx.x * 8 + (threadIdx.x >> 5);
    if (node >= n) return;
    const float* ar = a + (size_t)node * HID;
    float acc = 0.f;
#pragma unroll
    for (int k = 0; k < HID; ++k) acc += ar[k] * Wl[k * HID + ch];
    h[node * HID + ch] = acc;
}

// ---------------- CSR gather aggregation ----------------
// agg[i,ch] = dinv[i]^2 * h[i,ch] + b[ch] + sum_e norm[e]*h[src[e],ch]
__global__ void gather_csr(const float* __restrict__ h, const int* __restrict__ rowptr,
                           const int2* __restrict__ esort, const float* __restrict__ dinv,
                           const float* __restrict__ b, float* __restrict__ agg,
                           int n, int do_relu) {
    int ch = threadIdx.x & 31;
    int node = blockIdx.x * 8 + (threadIdx.x >> 5);
    if (node >= n) return;
    int start = rowptr[node];
    int end = rowptr[node + 1];
    float dv = dinv[node];
    float acc = dv * dv * h[node * HID + ch] + b[ch];
    for (int j = start; j < end; ++j) {
        int2 ed = esort[j];
        acc += __int_as_float(ed.y) * h[ed.x * HID + ch];
    }
    if (do_relu) acc = fmaxf(acc, 0.f);
    agg[node * HID + ch] = acc;
}

// ---------------- batchnorm ----------------
__global__ void zero_stats(float* s) {
    if (threadIdx.x < 64) s[threadIdx.x] = 0.f;
}

__global__ void bn_reduce(const float* __restrict__ agg, float* __restrict__ stats, int n) {
    __shared__ float s1[256], s2[256];
    int ch = threadIdx.x & 31, rg = threadIdx.x >> 5;
    float a = 0.f, b = 0.f;
    for (int node = blockIdx.x * 8 + rg; node < n; node += gridDim.x * 8) {
        float v = agg[node * HID + ch];
        a += v;
        b += v * v;
    }
    s1[threadIdx.x] = a;
    s2[threadIdx.x] = b;
    __syncthreads();
    if (threadIdx.x < 32) {
        float ta = 0.f, tb = 0.f;
#pragma unroll
        for (int j = 0; j < 8; ++j) {
            ta += s1[j * 32 + threadIdx.x];
            tb += s2[j * 32 + threadIdx.x];
        }
        atomicAdd(&stats[threadIdx.x], ta);
        atomicAdd(&stats[32 + threadIdx.x], tb);
    }
}

// in-place BN + ReLU
__global__ void bn_apply(float* __restrict__ agg, const float* __restrict__ stats,
                         const float* __restrict__ g, const float* __restrict__ be,
                         int n, float invN) {
    int gid = blockIdx.x * blockDim.x + threadIdx.x;
    if (gid >= n * HID) return;
    int ch = gid & 31;
    float mu = stats[ch] * invN;
    float var = stats[32 + ch] * invN - mu * mu;
    float v = (agg[gid] - mu) * rsqrtf(var + EPS) * g[ch] + be[ch];
    agg[gid] = fmaxf(v, 0.f);
}

extern "C" void kernel_launch(void* const* d_in, const int* in_sizes, int n_in,
                              void* d_out, int out_size, void* d_ws, size_t ws_size,
                              hipStream_t stream) {
    const int N = in_sizes[0] / DIN;
    const int E = in_sizes[2];

    const float* x = (const float*)d_in[0];
    const int* ei = (const int*)d_in[1];
    const float* ew = (const float*)d_in[2];
    const int* row = ei;
    const int* col = ei + E;

    const float* Ws[4] = {(const float*)d_in[3], (const float*)d_in[5],
                          (const float*)d_in[7], (const float*)d_in[9]};
    const float* bs[4] = {(const float*)d_in[4], (const float*)d_in[6],
                          (const float*)d_in[8], (const float*)d_in[10]};
    const float* gs[3] = {(const float*)d_in[11], (const float*)d_in[13], (const float*)d_in[15]};
    const float* bes[3] = {(const float*)d_in[12], (const float*)d_in[14], (const float*)d_in[16]};

    // workspace layout (~54 MB; rank aliases bufY — scatter finishes before gemms)
    float* ws = (float*)d_ws;
    unsigned long long* cnt64 = (unsigned long long*)ws;  // N u64
    float* dinv = (float*)(cnt64 + N);                    // N floats
    int* rowptr = (int*)(dinv + N);                       // N+1 ints
    int2* esort = (int2*)(rowptr + N + 1);                // E int2 (src, norm)
    float* bufX = (float*)(esort + E);                    // N*HID (act / agg)
    float* bufY = bufX + (size_t)N * HID;                 // N*HID (gemm out)
    float* stats = bufY + (size_t)N * HID;                // 64
    int* bsum = (int*)(stats + 64);                       // 512
    int* rank = (int*)bufY;                               // E ints, aliased (E*4 <= N*HID*4? no:
    // E=3.2M > N*HID=3.2M exactly equal -> 12.8MB each, fits exactly)

    const int B = 256;
    const int ngrid = (N + B - 1) / B;
    const int egrid = (E + B - 1) / B;
    const int ngrid32 = (N * HID + B - 1) / B;
    const int nodeGrid = (N + 7) / 8;
    const int scanBlocks = (N + 255) / 256;  // 391 <= 512
    const float invN = 1.0f / (float)N;

    // ---- build CSR + norm ----
    init_cnt<<<ngrid, B, 0, stream>>>(cnt64, N);
    hist_rank<<<egrid, B, 0, stream>>>(col, ew, cnt64, rank, E);
    finalize_deg<<<ngrid, B, 0, stream>>>(cnt64, rowptr, dinv, N);
    scan_blocks<<<scanBlocks, 256, 0, stream>>>(rowptr, bsum, N);
    scan_tops<<<1, 512, 0, stream>>>(bsum, scanBlocks);
    scan_addback<<<scanBlocks + 1, 256, 0, stream>>>(rowptr, bsum, N, E);
    scatter_pos<<<egrid, B, 0, stream>>>(row, col, ew, dinv, rowptr, rank, esort, E);

    // ---- layers ----
    for (int l = 0; l < 4; ++l) {
        if (l == 0)
            gemm_din<<<nodeGrid, B, 0, stream>>>(x, Ws[0], bufY, N);
        else
            gemm_hid<<<nodeGrid, B, 0, stream>>>(bufX, Ws[l], bufY, N);

        if (l < 3) {
            gather_csr<<<nodeGrid, B, 0, stream>>>(bufY, rowptr, esort, dinv, bs[l],
                                                   bufX, N, 0);
            zero_stats<<<1, 64, 0, stream>>>(stats);
            bn_reduce<<<512, B, 0, stream>>>(bufX, stats, N);
            bn_apply<<<ngrid32, B, 0, stream>>>(bufX, stats, gs[l], bes[l], N, invN);
        } else {
            gather_csr<<<nodeGrid, B, 0, stream>>>(bufY, rowptr, esort, dinv, bs[l],
                                                   (float*)d_out, N, 1);
        }
    }
}

// Round 6
// 899.207 us; speedup vs baseline: 2.1158x; 1.4215x over previous
//
#include <hip/hip_runtime.h>
#include <hip/hip_bf16.h>

#define DIN 128
#define HID 32
#define EPS 1e-5f
#define FXS 16777216.0f             // 2^24 fixed-point scale for deg accumulation
#define FXI 5.9604644775390625e-8f  // 2^-24

typedef unsigned int u32;
typedef unsigned short u16;
typedef unsigned long long u64;

// extract bf16 half (hi=0 -> low 16 bits = even channel, hi=1 -> high 16 bits) as float
__device__ __forceinline__ float bfx(u32 v, int hi) {
    return __uint_as_float(hi ? (v & 0xffff0000u) : (v << 16));
}

__device__ __forceinline__ u16 f2bf(float f) {
    __hip_bfloat16 h = __float2bfloat16(f);
    return *reinterpret_cast<u16*>(&h);
}

// ---------------- init: zero u64 count/deg accumulator + BN stats ----------------
__global__ void init_cnt(u64* __restrict__ cnt64, float* __restrict__ stats, int n) {
    int i = blockIdx.x * blockDim.x + threadIdx.x;
    if (i < n) cnt64[i] = 0ull;
    if (i < 192) stats[i] = 0.f;
}

// one u64 atomic per edge: count(hi32) + fixpoint deg(lo32); old hi32 = rank in bin
__global__ void hist_rank(const int* __restrict__ col, const float* __restrict__ w,
                          u64* __restrict__ cnt64, int* __restrict__ rank, int E) {
    int e = blockIdx.x * blockDim.x + threadIdx.x;
    if (e < E) {
        int c = col[e];
        u32 fx = (u32)(w[e] * FXS + 0.5f);
        u64 old = atomicAdd(&cnt64[c], (1ull << 32) | (u64)fx);
        rank[e] = (int)(old >> 32);
    }
}

// counts -> rowptr[i] (pre-scan), deg -> dinv
__global__ void finalize_deg(const u64* __restrict__ cnt64, int* __restrict__ rowptr,
                             float* __restrict__ dinv, int n) {
    int i = blockIdx.x * blockDim.x + threadIdx.x;
    if (i < n) {
        u64 v = cnt64[i];
        rowptr[i] = (int)(v >> 32);
        float deg = 1.0f + (float)(u32)v * FXI;  // +1 self loop
        dinv[i] = rsqrtf(deg);
    }
}

// ---------------- exclusive scan over rowptr[0..n) ----------------
__global__ void scan_blocks(int* __restrict__ data, int* __restrict__ bsum, int n) {
    __shared__ int s[256];
    int i = blockIdx.x * 256 + threadIdx.x;
    int v = (i < n) ? data[i] : 0;
    s[threadIdx.x] = v;
    __syncthreads();
    for (int off = 1; off < 256; off <<= 1) {
        int t = (threadIdx.x >= off) ? s[threadIdx.x - off] : 0;
        __syncthreads();
        s[threadIdx.x] += t;
        __syncthreads();
    }
    if (i < n) data[i] = s[threadIdx.x] - v;  // exclusive
    if (threadIdx.x == 255) bsum[blockIdx.x] = s[255];
}

__global__ void scan_tops(int* __restrict__ bsum, int nb) {
    __shared__ int s[512];
    int v = (threadIdx.x < nb) ? bsum[threadIdx.x] : 0;
    s[threadIdx.x] = v;
    __syncthreads();
    for (int off = 1; off < 512; off <<= 1) {
        int t = (threadIdx.x >= off) ? s[threadIdx.x - off] : 0;
        __syncthreads();
        s[threadIdx.x] += t;
        __syncthreads();
    }
    if (threadIdx.x < nb) bsum[threadIdx.x] = s[threadIdx.x] - v;  // exclusive
}

__global__ void scan_addback(int* __restrict__ data, const int* __restrict__ bsum,
                             int n, int E) {
    int i = blockIdx.x * 256 + threadIdx.x;
    if (i < n) data[i] += bsum[blockIdx.x];
    if (i == n) data[n] = E;  // sentinel end
}

// ---------------- atomic-free scatter into CSR ----------------
__global__ void scatter_pos(const int* __restrict__ row, const int* __restrict__ col,
                            const float* __restrict__ w, const float* __restrict__ dinv,
                            const int* __restrict__ rowptr, const int* __restrict__ rank,
                            int2* __restrict__ esort, int E) {
    int e = blockIdx.x * blockDim.x + threadIdx.x;
    if (e < E) {
        int r = row[e], c = col[e];
        float nv = dinv[r] * w[e] * dinv[c];
        int pos = rowptr[c] + rank[e];
        esort[pos] = make_int2(r, __float_as_int(nv));
    }
}

// ---------------- GEMMs (output bf16) ----------------
__global__ void gemm_din(const float* __restrict__ x, const float* __restrict__ W,
                         u16* __restrict__ hb, int n) {
    __shared__ float Wl[DIN * HID];
    for (int i = threadIdx.x; i < DIN * HID; i += blockDim.x) Wl[i] = W[i];
    __syncthreads();
    int ch = threadIdx.x & 31;
    int node = blockIdx.x * 8 + (threadIdx.x >> 5);
    if (node >= n) return;
    const float* xr = x + (size_t)node * DIN;
    float acc = 0.f;
#pragma unroll 8
    for (int k = 0; k < DIN; ++k) acc += xr[k] * Wl[k * HID + ch];
    hb[node * HID + ch] = f2bf(acc);
}

__global__ void gemm_hid(const float* __restrict__ a, const float* __restrict__ W,
                         u16* __restrict__ hb, int n) {
    __shared__ float Wl[HID * HID];
    for (int i = threadIdx.x; i < HID * HID; i += blockDim.x) Wl[i] = W[i];
    __syncthreads();
    int ch = threadIdx.x & 31;
    int node = blockIdx.x * 8 + (threadIdx.x >> 5);
    if (node >= n) return;
    const float* ar = a + (size_t)node * HID;
    float acc = 0.f;
#pragma unroll
    for (int k = 0; k < HID; ++k) acc += ar[k] * Wl[k * HID + ch];
    hb[node * HID + ch] = f2bf(acc);
}

// ---------------- CSR gather aggregation (bf16 h, fp32 accumulate) ----------------
// agg[i,ch] = dinv[i]^2 * h[i,ch] + b[ch] + sum_e norm[e]*h[src[e],ch]
// lane ch reads u32 word (ch>>1), half (ch&1)  => channel 2*(ch>>1)+(ch&1) == ch
__global__ void gather_bf16(const u32* __restrict__ h2, const int* __restrict__ rowptr,
                            const int2* __restrict__ esort, const float* __restrict__ dinv,
                            const float* __restrict__ b, float* __restrict__ agg,
                            int n, int do_relu) {
    int ch = threadIdx.x & 31;
    int node = blockIdx.x * 8 + (threadIdx.x >> 5);
    if (node >= n) return;
    int p = ch >> 1, hi = ch & 1;
    int start = rowptr[node], end = rowptr[node + 1];
    float dv = dinv[node];
    float acc = dv * dv * bfx(h2[node * 16 + p], hi) + b[ch];
    int j = start;
    for (; j + 4 <= end; j += 4) {
        int2 e0 = esort[j];
        int2 e1 = esort[j + 1];
        int2 e2 = esort[j + 2];
        int2 e3 = esort[j + 3];
        u32 v0 = h2[e0.x * 16 + p];
        u32 v1 = h2[e1.x * 16 + p];
        u32 v2 = h2[e2.x * 16 + p];
        u32 v3 = h2[e3.x * 16 + p];
        acc += __int_as_float(e0.y) * bfx(v0, hi);
        acc += __int_as_float(e1.y) * bfx(v1, hi);
        acc += __int_as_float(e2.y) * bfx(v2, hi);
        acc += __int_as_float(e3.y) * bfx(v3, hi);
    }
    for (; j < end; ++j) {
        int2 ed = esort[j];
        acc += __int_as_float(ed.y) * bfx(h2[ed.x * 16 + p], hi);
    }
    if (do_relu) acc = fmaxf(acc, 0.f);
    agg[node * HID + ch] = acc;
}

// ---------------- batchnorm ----------------
__global__ void bn_reduce(const float* __restrict__ agg, float* __restrict__ stats, int n) {
    __shared__ float s1[256], s2[256];
    int ch = threadIdx.x & 31, rg = threadIdx.x >> 5;
    float a = 0.f, b = 0.f;
    for (int node = blockIdx.x * 8 + rg; node < n; node += gridDim.x * 8) {
        float v = agg[node * HID + ch];
        a += v;
        b += v * v;
    }
    s1[threadIdx.x] = a;
    s2[threadIdx.x] = b;
    __syncthreads();
    if (threadIdx.x < 32) {
        float ta = 0.f, tb = 0.f;
#pragma unroll
        for (int j = 0; j < 8; ++j) {
            ta += s1[j * 32 + threadIdx.x];
            tb += s2[j * 32 + threadIdx.x];
        }
        atomicAdd(&stats[threadIdx.x], ta);
        atomicAdd(&stats[32 + threadIdx.x], tb);
    }
}

// in-place BN + ReLU
__global__ void bn_apply(float* __restrict__ agg, const float* __restrict__ stats,
                         const float* __restrict__ g, const float* __restrict__ be,
                         int n, float invN) {
    int gid = blockIdx.x * blockDim.x + threadIdx.x;
    if (gid >= n * HID) return;
    int ch = gid & 31;
    float mu = stats[ch] * invN;
    float var = stats[32 + ch] * invN - mu * mu;
    float v = (agg[gid] - mu) * rsqrtf(var + EPS) * g[ch] + be[ch];
    agg[gid] = fmaxf(v, 0.f);
}

extern "C" void kernel_launch(void* const* d_in, const int* in_sizes, int n_in,
                              void* d_out, int out_size, void* d_ws, size_t ws_size,
                              hipStream_t stream) {
    const int N = in_sizes[0] / DIN;
    const int E = in_sizes[2];

    const float* x = (const float*)d_in[0];
    const int* ei = (const int*)d_in[1];
    const float* ew = (const float*)d_in[2];
    const int* row = ei;
    const int* col = ei + E;

    const float* Ws[4] = {(const float*)d_in[3], (const float*)d_in[5],
                          (const float*)d_in[7], (const float*)d_in[9]};
    const float* bs[4] = {(const float*)d_in[4], (const float*)d_in[6],
                          (const float*)d_in[8], (const float*)d_in[10]};
    const float* gs[3] = {(const float*)d_in[11], (const float*)d_in[13], (const float*)d_in[15]};
    const float* bes[3] = {(const float*)d_in[12], (const float*)d_in[14], (const float*)d_in[16]};

    // workspace layout (~46 MB)
    char* wsb = (char*)d_ws;
    u64* cnt64 = (u64*)wsb;                          // N u64
    float* dinv = (float*)(cnt64 + N);               // N f32
    int* rowptr = (int*)(dinv + N);                  // N+1 int
    int2* esort = (int2*)(rowptr + N + 1);           // E int2 (src, norm)
    u16* hbf = (u16*)(esort + E);                    // N*HID bf16 (gemm out)
    float* bufX = (float*)(hbf + (size_t)N * HID);   // N*HID f32 (agg / act, BN in place)
    float* stats = bufX + (size_t)N * HID;           // 192 (3 layers x 64)
    int* bsum = (int*)(stats + 192);                 // 512
    int* rank = (int*)bufX;  // E ints aliased: rank dead before bufX first written

    const int B = 256;
    const int ngrid = (N + B - 1) / B;
    const int egrid = (E + B - 1) / B;
    const int ngrid32 = (N * HID + B - 1) / B;
    const int nodeGrid = (N + 7) / 8;
    const int scanBlocks = (N + 255) / 256;  // 391 <= 512
    const float invN = 1.0f / (float)N;

    // ---- build CSR + norm ----
    init_cnt<<<ngrid, B, 0, stream>>>(cnt64, stats, N);
    hist_rank<<<egrid, B, 0, stream>>>(col, ew, cnt64, rank, E);
    finalize_deg<<<ngrid, B, 0, stream>>>(cnt64, rowptr, dinv, N);
    scan_blocks<<<scanBlocks, 256, 0, stream>>>(rowptr, bsum, N);
    scan_tops<<<1, 512, 0, stream>>>(bsum, scanBlocks);
    scan_addback<<<scanBlocks + 1, 256, 0, stream>>>(rowptr, bsum, N, E);
    scatter_pos<<<egrid, B, 0, stream>>>(row, col, ew, dinv, rowptr, rank, esort, E);

    // ---- layers ----
    for (int l = 0; l < 4; ++l) {
        if (l == 0)
            gemm_din<<<nodeGrid, B, 0, stream>>>(x, Ws[0], hbf, N);
        else
            gemm_hid<<<nodeGrid, B, 0, stream>>>(bufX, Ws[l], hbf, N);

        if (l < 3) {
            gather_bf16<<<nodeGrid, B, 0, stream>>>((const u32*)hbf, rowptr, esort, dinv,
                                                    bs[l], bufX, N, 0);
            bn_reduce<<<512, B, 0, stream>>>(bufX, stats + 64 * l, N);
            bn_apply<<<ngrid32, B, 0, stream>>>(bufX, stats + 64 * l, gs[l], bes[l], N, invN);
        } else {
            gather_bf16<<<nodeGrid, B, 0, stream>>>((const u32*)hbf, rowptr, esort, dinv,
                                                    bs[l], (float*)d_out, N, 1);
        }
    }
}